// Round 1
// baseline (943.372 us; speedup 1.0000x reference)
//
#include <hip/hip_runtime.h>
#include <cstdint>

typedef unsigned short u16;
typedef u16   u16x8 __attribute__((ext_vector_type(8)));
typedef short s16x8 __attribute__((ext_vector_type(8)));
typedef float f32x4 __attribute__((ext_vector_type(4)));

__device__ __forceinline__ u16 f2bf(float f) {
  union { float f; unsigned u; } v; v.f = f;
  unsigned u = v.u;
  return (u16)((u + 0x7fffu + ((u >> 16) & 1u)) >> 16);
}

__device__ __forceinline__ void gld_lds16(const u16* g, u16* l) {
  __builtin_amdgcn_global_load_lds((const __attribute__((address_space(1))) void*)g,
                                   (__attribute__((address_space(3))) void*)l, 16, 0, 0);
}

// ---------------- elementwise cast fp32 -> bf16 ----------------
__global__ void cast_f32_bf16_k(const float* __restrict__ in, u16* __restrict__ out) {
  size_t i = ((size_t)blockIdx.x * 256 + threadIdx.x) * 8;
  float4 a = *(const float4*)(in + i);
  float4 b = *(const float4*)(in + i + 4);
  u16x8 r;
  r[0] = f2bf(a.x); r[1] = f2bf(a.y); r[2] = f2bf(a.z); r[3] = f2bf(a.w);
  r[4] = f2bf(b.x); r[5] = f2bf(b.y); r[6] = f2bf(b.z); r[7] = f2bf(b.w);
  *(u16x8*)(out + i) = r;
}

// ---------------- transpose+cast fp32 [R][Cin] -> bf16 [Cin][R] ----------------
__global__ void transpose_cast_f32_k(const float* __restrict__ in, u16* __restrict__ outp,
                                     int R, int Cin) {
  __shared__ u16 tile[64][72];
  const int c0 = blockIdx.x * 64, r0 = blockIdx.y * 64;
  const int t = threadIdx.x;
  const int r = t >> 2, cs = (t & 3) * 16;
  const float* src = in + (size_t)(r0 + r) * Cin + c0 + cs;
#pragma unroll
  for (int q = 0; q < 4; ++q) {
    float4 v = *(const float4*)(src + q * 4);
    tile[r][cs + q * 4 + 0] = f2bf(v.x);
    tile[r][cs + q * 4 + 1] = f2bf(v.y);
    tile[r][cs + q * 4 + 2] = f2bf(v.z);
    tile[r][cs + q * 4 + 3] = f2bf(v.w);
  }
  __syncthreads();
  u16x8 w0, w1;
#pragma unroll
  for (int q = 0; q < 8; ++q) { w0[q] = tile[cs + q][r]; w1[q] = tile[cs + 8 + q][r]; }
  u16* dst = outp + (size_t)(c0 + r) * R + r0 + cs;
  *(u16x8*)dst = w0;
  *(u16x8*)(dst + 8) = w1;
}

// ---------------- transpose bf16 V [bh][T][D] -> Vt [bh][D][T] ----------------
__global__ void transpose_v_k(const u16* __restrict__ V, u16* __restrict__ Vt) {
  __shared__ u16 tile[64][72];
  const int t0 = blockIdx.x * 64, d0 = blockIdx.y * 64, bh = blockIdx.z;
  const int t = threadIdx.x;
  const int r = t >> 2, cs = (t & 3) * 16;
  const u16* src = V + ((size_t)bh * 2048 + t0 + r) * 128 + d0 + cs;
  u16x8 a0 = *(const u16x8*)src;
  u16x8 a1 = *(const u16x8*)(src + 8);
#pragma unroll
  for (int q = 0; q < 8; ++q) { tile[r][cs + q] = a0[q]; tile[r][cs + 8 + q] = a1[q]; }
  __syncthreads();
  u16x8 w0, w1;
#pragma unroll
  for (int q = 0; q < 8; ++q) { w0[q] = tile[cs + q][r]; w1[q] = tile[cs + 8 + q][r]; }
  u16* dst = Vt + ((size_t)bh * 128 + d0 + r) * 2048 + t0 + cs;
  *(u16x8*)dst = w0;
  *(u16x8*)(dst + 8) = w1;
}

// ---------------- GEMM: C[M,N] = A[M,K] * Bt[N,K]^T + bias ----------------
// EPI 0: scatter into Q/K/V bf16 [B,H,T,D]; EPI 1: fp32 out [M,2048]
template <int EPI>
__global__ __launch_bounds__(256, 2) void gemm_bt(
    const u16* __restrict__ A, const u16* __restrict__ Bt,
    const float* __restrict__ bias,
    u16* __restrict__ o0, u16* __restrict__ o1, u16* __restrict__ o2,
    float* __restrict__ ofp, int Ntiles, int Kdim) {
  __shared__ u16 As[2][4096];  // [khi*128+row] 16B chunks
  __shared__ u16 Bs[2][4096];
  const int bid = blockIdx.x;
  const int mt = bid / Ntiles, nt = bid % Ntiles;
  const int tid = threadIdx.x, lane = tid & 63, wave = tid >> 6;
  const int wr = wave >> 1, wc = wave & 1;
  f32x4 acc[4][4] = {};
  const int nK = Kdim >> 5;
  const size_t ldA = (size_t)Kdim;

#define STAGE(buf, kt)                                                              \
  {                                                                                 \
    int k0 = (kt) << 5;                                                             \
    for (int j = 0; j < 2; ++j) {                                                   \
      int idx = (wave * 2 + j) * 64 + lane;                                         \
      int khi = idx >> 7, row = idx & 127;                                          \
      gld_lds16(A + (size_t)(mt * 128 + row) * ldA + k0 + khi * 8,                  \
                &As[buf][(wave * 2 + j) * 512]);                                    \
      gld_lds16(Bt + (size_t)(nt * 128 + row) * ldA + k0 + khi * 8,                 \
                &Bs[buf][(wave * 2 + j) * 512]);                                    \
    }                                                                               \
  }

  STAGE(0, 0);
  __syncthreads();
  int cur = 0;
  for (int kt = 0; kt < nK; ++kt) {
    if (kt + 1 < nK) STAGE(cur ^ 1, kt + 1);
    s16x8 af[4], bfr[4];
#pragma unroll
    for (int mi = 0; mi < 4; ++mi)
      af[mi] = *(const s16x8*)&As[cur][(((lane >> 4) * 128) + wr * 64 + mi * 16 + (lane & 15)) * 8];
#pragma unroll
    for (int ni = 0; ni < 4; ++ni)
      bfr[ni] = *(const s16x8*)&Bs[cur][(((lane >> 4) * 128) + wc * 64 + ni * 16 + (lane & 15)) * 8];
#pragma unroll
    for (int mi = 0; mi < 4; ++mi)
#pragma unroll
      for (int ni = 0; ni < 4; ++ni)
        acc[mi][ni] = __builtin_amdgcn_mfma_f32_16x16x32_bf16(af[mi], bfr[ni], acc[mi][ni], 0, 0, 0);
    __syncthreads();
    cur ^= 1;
  }
#undef STAGE

  const int row0 = mt * 128 + wr * 64;
  const int col0 = nt * 128 + wc * 64;
  if constexpr (EPI == 0) {
    const int nbase = nt * 128;
    const int which = nbase >> 11;           // 0:Q 1:K 2:V
    const int h = (nbase >> 7) & 15;         // head (tile spans exactly one head)
    u16* o = (which == 0) ? o0 : (which == 1) ? o1 : o2;
#pragma unroll
    for (int mi = 0; mi < 4; ++mi)
#pragma unroll
      for (int ni = 0; ni < 4; ++ni)
#pragma unroll
        for (int j = 0; j < 4; ++j) {
          int row = row0 + mi * 16 + (lane >> 4) * 4 + j;  // global token row
          int col = col0 + ni * 16 + (lane & 15);          // global qkv col
          float v = acc[mi][ni][j] + bias[col];
          int bb = row >> 11, t = row & 2047;
          int d = col & 127;
          o[(((size_t)bb * 16 + h) * 2048 + t) * 128 + d] = f2bf(v);
        }
  } else {
#pragma unroll
    for (int mi = 0; mi < 4; ++mi)
#pragma unroll
      for (int ni = 0; ni < 4; ++ni)
#pragma unroll
        for (int j = 0; j < 4; ++j) {
          int row = row0 + mi * 16 + (lane >> 4) * 4 + j;
          int col = col0 + ni * 16 + (lane & 15);
          ofp[(size_t)row * 2048 + col] = acc[mi][ni][j] + bias[col];
        }
  }
}

// ---------------- flash attention: 64 q-rows/block, 4 waves x 16 rows ----------------
__global__ __launch_bounds__(256, 2) void attn_k(
    const u16* __restrict__ Q, const u16* __restrict__ Kg,
    const u16* __restrict__ Vt, u16* __restrict__ Y) {
  __shared__ u16 Ks[8192];        // 16 dhi x 64 key, 16B chunks
  __shared__ u16 Vs[8192];        // 8 khi x 128 d, 16B chunks
  __shared__ u16 Ps[4][16 * 72];  // per-wave P tile, padded rows
  const int qt = blockIdx.x, bh = blockIdx.y;
  const int tid = threadIdx.x, lane = tid & 63, wave = tid >> 6;
  const int r0 = qt * 64 + wave * 16;
  const size_t bhT = (size_t)bh * 2048;

  s16x8 qf[4];
#pragma unroll
  for (int kk = 0; kk < 4; ++kk)
    qf[kk] = *(const s16x8*)&Q[(bhT + r0 + (lane & 15)) * 128 + kk * 32 + (lane >> 4) * 8];

  f32x4 o[8] = {};
  float m_[4], l_[4];
#pragma unroll
  for (int j = 0; j < 4; ++j) { m_[j] = -1e30f; l_[j] = 0.f; }
  const float sc = 0.08838834764831845f * 1.4426950408889634f;  // 1/sqrt(128) * log2(e)

  for (int it = 0; it <= qt; ++it) {
    const int j0 = it * 64;
    __syncthreads();  // previous tile's LDS reads done before restage
#pragma unroll
    for (int j = 0; j < 4; ++j) {
      int idx = (wave * 4 + j) * 64 + lane;
      int dhi = idx >> 6, key = idx & 63;
      gld_lds16(Kg + (bhT + j0 + key) * 128 + dhi * 8, &Ks[(wave * 4 + j) * 512]);
      int khi = idx >> 7, d = idx & 127;
      gld_lds16(Vt + ((size_t)bh * 128 + d) * 2048 + j0 + khi * 8, &Vs[(wave * 4 + j) * 512]);
    }
    __syncthreads();  // drains vmcnt: K/V staged

    // S = Q K^T (per wave: 16 q-rows x 64 keys)
    f32x4 s[4] = {};
#pragma unroll
    for (int nc = 0; nc < 4; ++nc) {
#pragma unroll
      for (int kk = 0; kk < 4; ++kk) {
        s16x8 kf = *(const s16x8*)&Ks[((kk * 4 + (lane >> 4)) * 64 + nc * 16 + (lane & 15)) * 8];
        s[nc] = __builtin_amdgcn_mfma_f32_16x16x32_bf16(qf[kk], kf, s[nc], 0, 0, 0);
      }
    }
    const bool lastT = (it == qt);
    float rmax[4];
#pragma unroll
    for (int j = 0; j < 4; ++j) rmax[j] = -1e30f;
#pragma unroll
    for (int nc = 0; nc < 4; ++nc)
#pragma unroll
      for (int j = 0; j < 4; ++j) {
        float v = s[nc][j] * sc;
        if (lastT && (j0 + nc * 16 + (lane & 15)) > (r0 + (lane >> 4) * 4 + j)) v = -1e30f;
        s[nc][j] = v;
        rmax[j] = fmaxf(rmax[j], v);
      }
#pragma unroll
    for (int off = 1; off < 16; off <<= 1)
#pragma unroll
      for (int j = 0; j < 4; ++j) rmax[j] = fmaxf(rmax[j], __shfl_xor(rmax[j], off));

    float al[4], rsum[4];
#pragma unroll
    for (int j = 0; j < 4; ++j) {
      float mn = fmaxf(m_[j], rmax[j]);
      al[j] = exp2f(m_[j] - mn);
      m_[j] = mn;
      rsum[j] = 0.f;
    }
#pragma unroll
    for (int nc = 0; nc < 4; ++nc)
#pragma unroll
      for (int j = 0; j < 4; ++j) {
        float p = exp2f(s[nc][j] - m_[j]);
        rsum[j] += p;
        Ps[wave][((lane >> 4) * 4 + j) * 72 + nc * 16 + (lane & 15)] = f2bf(p);
      }
#pragma unroll
    for (int off = 1; off < 16; off <<= 1)
#pragma unroll
      for (int j = 0; j < 4; ++j) rsum[j] += __shfl_xor(rsum[j], off);
#pragma unroll
    for (int j = 0; j < 4; ++j) l_[j] = l_[j] * al[j] + rsum[j];
#pragma unroll
    for (int di = 0; di < 8; ++di)
#pragma unroll
      for (int j = 0; j < 4; ++j) o[di][j] *= al[j];

    // O += P V  (P via LDS round-trip to get A-fragment layout)
#pragma unroll
    for (int kk2 = 0; kk2 < 2; ++kk2) {
      s16x8 pf = *(const s16x8*)&Ps[wave][(lane & 15) * 72 + kk2 * 32 + (lane >> 4) * 8];
#pragma unroll
      for (int di = 0; di < 8; ++di) {
        s16x8 vf = *(const s16x8*)&Vs[((kk2 * 4 + (lane >> 4)) * 128 + di * 16 + (lane & 15)) * 8];
        o[di] = __builtin_amdgcn_mfma_f32_16x16x32_bf16(pf, vf, o[di], 0, 0, 0);
      }
    }
  }

  float rl[4];
#pragma unroll
  for (int j = 0; j < 4; ++j) rl[j] = 1.0f / l_[j];
  const int b = bh >> 4, h = bh & 15;
#pragma unroll
  for (int di = 0; di < 8; ++di)
#pragma unroll
    for (int j = 0; j < 4; ++j) {
      int row = b * 2048 + r0 + (lane >> 4) * 4 + j;
      int col = h * 128 + di * 16 + (lane & 15);
      Y[(size_t)row * 2048 + col] = f2bf(o[di][j] * rl[j]);
    }
}

extern "C" void kernel_launch(void* const* d_in, const int* in_sizes, int n_in,
                              void* d_out, int out_size, void* d_ws, size_t ws_size,
                              hipStream_t stream) {
  const float* x      = (const float*)d_in[0];
  const float* w_attn = (const float*)d_in[1];
  const float* b_attn = (const float*)d_in[2];
  const float* w_proj = (const float*)d_in[3];
  const float* b_proj = (const float*)d_in[4];
  float* out = (float*)d_out;

  char* ws = (char*)d_ws;
  u16* xb  = (u16*)(ws);                      // 33,554,432 B  x bf16 [8192][2048]
  u16* waT = (u16*)(ws + 33554432ull);        // 25,165,824 B  w_attn^T bf16 [6144][2048]
  u16* wpT = (u16*)(ws + 58720256ull);        //  8,388,608 B  w_proj^T bf16 [2048][2048]
  u16* Qb  = (u16*)(ws + 67108864ull);        // 33,554,432 B  [B,H,T,D]
  u16* Kb  = (u16*)(ws + 100663296ull);       // 33,554,432 B
  u16* Vb  = (u16*)(ws + 134217728ull);       // 33,554,432 B
  u16* Vtb = (u16*)(ws + 167772160ull);       // 33,554,432 B  [B,H,D,T]
  u16* Yb  = xb;                              // reuse (xb dead after gemm1)

  cast_f32_bf16_k<<<8192, 256, 0, stream>>>(x, xb);
  transpose_cast_f32_k<<<dim3(96, 32), 256, 0, stream>>>(w_attn, waT, 2048, 6144);
  transpose_cast_f32_k<<<dim3(32, 32), 256, 0, stream>>>(w_proj, wpT, 2048, 2048);
  gemm_bt<0><<<64 * 48, 256, 0, stream>>>(xb, waT, b_attn, Qb, Kb, Vb, nullptr, 48, 2048);
  transpose_v_k<<<dim3(32, 2, 64), 256, 0, stream>>>(Vb, Vtb);
  attn_k<<<dim3(32, 64), 256, 0, stream>>>(Qb, Kb, Vtb, Yb);
  gemm_bt<1><<<64 * 16, 256, 0, stream>>>(Yb, wpT, b_proj, nullptr, nullptr, nullptr, out, 16, 2048);
}